// Round 2
// baseline (2096.728 us; speedup 1.0000x reference)
//
#include <hip/hip_runtime.h>
#include <hip/hip_bf16.h>

typedef unsigned short u16;
typedef __attribute__((ext_vector_type(4))) float f32x4;
typedef __attribute__((ext_vector_type(8))) short short8;
typedef __attribute__((ext_vector_type(8))) u16 us8;

// Geometry (fixed): B=64, N=256, DIM=2048, H=8, D=256; M=B*N=16384; qkvN=6144
// Per-head planes: [512][256][256]

__device__ __forceinline__ u16 f2bf(float f) {
  union { float f; unsigned u; } v; v.f = f;
  unsigned r = v.u + 0x7fffu + ((v.u >> 16) & 1u);   // RNE, finite inputs
  return (u16)(r >> 16);
}
__device__ __forceinline__ float bf2f(u16 h) {
  union { unsigned u; float f; } v; v.u = ((unsigned)h) << 16; return v.f;
}

// ---------- diagnostic beacon: absmax ~= ws_size in MiB ----------
__global__ void beacon_kernel(float* __restrict__ out, float val, int n) {
  int stride = gridDim.x * blockDim.x;
  for (int i = blockIdx.x * blockDim.x + threadIdx.x; i < n; i += stride)
    out[i] = val;
}

// ---------- prep: fp32 -> bf16 hi (+ optional lo residual) ----------
__global__ void split_kernel(const float* __restrict__ in, u16* __restrict__ hi,
                             u16* __restrict__ lo, int n4) {
  int stride = gridDim.x * blockDim.x;
  for (int i = blockIdx.x * blockDim.x + threadIdx.x; i < n4; i += stride) {
    f32x4 v = ((const f32x4*)in)[i];
    ushort4 h;
    h.x = f2bf(v[0]); h.y = f2bf(v[1]); h.z = f2bf(v[2]); h.w = f2bf(v[3]);
    ((ushort4*)hi)[i] = h;
    if (lo) {
      ushort4 l;
      l.x = f2bf(v[0] - bf2f(h.x)); l.y = f2bf(v[1] - bf2f(h.y));
      l.z = f2bf(v[2] - bf2f(h.z)); l.w = f2bf(v[3] - bf2f(h.w));
      ((ushort4*)lo)[i] = l;
    }
  }
}

// ---------- NT GEMM skeleton: C[M,N] = A[M,K] * B[N,K]^T ----------
// MODE 0: qkv fast (bf16 split inputs, global_load_lds) -> q/k/v scatter
// MODE 1: logits S^T = kT * q^T (split, batched z) -> fp32 S (group-local)
// MODE 2: PV: P * vT^T (plain, batched z) -> bf16 attn [b*256+i][h*256+d]
// MODE 3: proj (plain) -> fp32 out + bias
// MODE 4: qkv slow (fp32 inputs, reg-stage + on-the-fly hi/lo split)
template<int MODE>
__global__ __launch_bounds__(256)
void gemm_nt(const u16* __restrict__ Ah, const u16* __restrict__ Al,
             const u16* __restrict__ Bh, const u16* __restrict__ Bl,
             const float* __restrict__ Af, const float* __restrict__ Bf,
             u16* __restrict__ qh, u16* __restrict__ ql,
             u16* __restrict__ kh, u16* __restrict__ kl,
             u16* __restrict__ vv,
             float* __restrict__ sout, u16* __restrict__ aout,
             float* __restrict__ fout, const float* __restrict__ bias,
             int ldA, int ldB, int ksteps, int plane_base) {
  constexpr bool SPLIT = (MODE == 0 || MODE == 1 || MODE == 4);
  __shared__ __align__(16) u16 lds[16384];       // 4 slots x [128][32] bf16
  u16* sAh = lds;         u16* sAl = lds + 4096;
  u16* sBh = lds + 8192;  u16* sBl = lds + 12288;

  const int tid  = threadIdx.x;
  const int wave = tid >> 6;
  const int lane = tid & 63;
  const int wr = wave >> 1, wc = wave & 1;       // 2x2 wave grid, 64x64 each
  const int l15 = lane & 15, l16 = lane >> 4;

  size_t zoffA = 0, zoffB = 0;
  if constexpr (MODE == 1) {
    size_t gz = (size_t)(plane_base + blockIdx.z) * 65536;
    zoffA = gz; zoffB = gz;
  }
  if constexpr (MODE == 2) {
    zoffA = (size_t)blockIdx.z * 65536;                     // P: group-local
    zoffB = (size_t)(plane_base + blockIdx.z) * 65536;      // v: global plane
  }
  const u16* A_h = Ah + zoffA;
  const u16* B_h = Bh + zoffB;
  const u16* A_l = (SPLIT && Al) ? Al + zoffA : nullptr;
  const u16* B_l = (SPLIT && Bl) ? Bl + zoffB : nullptr;

  const int m0 = blockIdx.x * 128;
  const int n0 = blockIdx.y * 128;

  f32x4 acc[4][4] = {};

  // bf16 staging: 128x32 tile via global_load_lds (wave-uniform LDS base).
  auto stage = [&](const u16* g, int ld, u16* slot, int row0, int k0) {
    #pragma unroll
    for (int c = 0; c < 2; ++c) {
      int chunk = wave + c * 4;
      int r = chunk * 16 + (lane >> 2);
      int col = (lane & 3) * 8;
      const u16* src = g + (size_t)(row0 + r) * ld + (k0 + col);
      __builtin_amdgcn_global_load_lds(
          (const __attribute__((address_space(1))) unsigned*)src,
          (__attribute__((address_space(3))) unsigned*)(slot + chunk * 512),
          16, 0, 0);
    }
  };
  // fp32 reg-staging with on-the-fly hi/lo split.
  auto stage_f32 = [&](const float* g, int ld, u16* hi, u16* lo, int row0, int k0) {
    #pragma unroll
    for (int p = 0; p < 4; ++p) {
      int r = p * 32 + wave * 8 + (lane >> 3);
      int c = (lane & 7) * 4;
      f32x4 v = *(const f32x4*)(g + (size_t)(row0 + r) * ld + k0 + c);
      ushort4 h, l;
      h.x = f2bf(v[0]); h.y = f2bf(v[1]); h.z = f2bf(v[2]); h.w = f2bf(v[3]);
      l.x = f2bf(v[0] - bf2f(h.x)); l.y = f2bf(v[1] - bf2f(h.y));
      l.z = f2bf(v[2] - bf2f(h.z)); l.w = f2bf(v[3] - bf2f(h.w));
      *(ushort4*)(hi + r * 32 + c) = h;
      *(ushort4*)(lo + r * 32 + c) = l;
    }
  };

  for (int ks = 0; ks < ksteps; ++ks) {
    int k0 = ks * 32;
    if constexpr (MODE == 4) {
      stage_f32(Af, ldA, sAh, sAl, m0, k0);
      stage_f32(Bf, ldB, sBh, sBl, n0, k0);
    } else {
      stage(A_h, ldA, sAh, m0, k0);
      stage(B_h, ldB, sBh, n0, k0);
      if constexpr (SPLIT) {
        stage(A_l, ldA, sAl, m0, k0);
        stage(B_l, ldB, sBl, n0, k0);
      }
    }
    __syncthreads();   // staged tiles visible (drains vmcnt/lgkmcnt)

    short8 a_h[4], b_h[4], a_l[4], b_l[4];
    #pragma unroll
    for (int i = 0; i < 4; ++i) {
      int ra = (wr * 64 + i * 16 + l15) * 4 + l16;   // short8 idx in [128][32]
      int rb = (wc * 64 + i * 16 + l15) * 4 + l16;
      a_h[i] = ((const short8*)sAh)[ra];
      b_h[i] = ((const short8*)sBh)[rb];
      if constexpr (SPLIT) {
        a_l[i] = ((const short8*)sAl)[ra];
        b_l[i] = ((const short8*)sBl)[rb];
      }
    }
    #pragma unroll
    for (int i = 0; i < 4; ++i)
      #pragma unroll
      for (int j = 0; j < 4; ++j) {
        acc[i][j] = __builtin_amdgcn_mfma_f32_16x16x32_bf16(a_h[i], b_h[j], acc[i][j], 0, 0, 0);
        if constexpr (SPLIT) {
          acc[i][j] = __builtin_amdgcn_mfma_f32_16x16x32_bf16(a_h[i], b_l[j], acc[i][j], 0, 0, 0);
          acc[i][j] = __builtin_amdgcn_mfma_f32_16x16x32_bf16(a_l[i], b_h[j], acc[i][j], 0, 0, 0);
        }
      }
    __syncthreads();   // reads done before next stage overwrites
  }

  // epilogue: C/D layout (m89/m91): col = lane&15, row = (lane>>4)*4 + reg
  #pragma unroll
  for (int i = 0; i < 4; ++i)
    #pragma unroll
    for (int j = 0; j < 4; ++j)
      #pragma unroll
      for (int r = 0; r < 4; ++r) {
        int gm = m0 + wr * 64 + i * 16 + l16 * 4 + r;
        int gn = n0 + wc * 64 + j * 16 + l15;
        float val = acc[i][j][r];
        if constexpr (MODE == 0 || MODE == 4) {
          int b = gm >> 8, tok = gm & 255;
          int sel = gn >> 11, c2 = gn & 2047;          // 0=q 1=k 2=v
          size_t addr = ((((size_t)b * 8 + (c2 >> 8)) * 256 + tok) * 256) + (c2 & 255);
          u16 h = f2bf(val);
          if (sel == 0)      { qh[addr] = h; ql[addr] = f2bf(val - bf2f(h)); }
          else if (sel == 1) { kh[addr] = h; kl[addr] = f2bf(val - bf2f(h)); }
          else               { vv[addr] = h; }
        } else if constexpr (MODE == 1) {
          sout[(size_t)blockIdx.z * 65536 + (size_t)gm * 256 + gn] = val;
        } else if constexpr (MODE == 2) {
          int gp = plane_base + blockIdx.z;
          size_t row = (size_t)(gp >> 3) * 256 + gm;     // b*256 + i
          size_t col = (size_t)(gp & 7) * 256 + gn;      // h*256 + d
          aout[row * 2048 + col] = f2bf(val);
        } else {
          fout[(size_t)gm * 2048 + gn] = val + bias[gn];
        }
      }
}

// ---------- per-head 256x256 in-place transpose (k_hi, k_lo, v) ----------
__global__ void transpose_inplace(u16* __restrict__ kh, u16* __restrict__ kl,
                                  u16* __restrict__ v) {
  __shared__ u16 ta[64][66], tb[64][66];
  u16* base = (blockIdx.z == 0) ? kh : (blockIdx.z == 1) ? kl : v;
  u16* pl = base + (size_t)blockIdx.y * 65536;
  const int RA[10] = {0,1,2,3, 0,0,0,1,1,2};
  const int CA[10] = {0,1,2,3, 1,2,3,2,3,3};
  int p = blockIdx.x;
  int R = RA[p], C = CA[p];
  bool diag = (R == C);
  int tid = threadIdx.x;
  int r = tid >> 2, c0 = (tid & 3) * 16;

  const us8* sa = (const us8*)(pl + (size_t)(R * 64 + r) * 256 + C * 64 + c0);
  us8 a0 = sa[0], a1 = sa[1];
  #pragma unroll
  for (int s = 0; s < 8; ++s) { ta[r][c0 + s] = a0[s]; ta[r][c0 + 8 + s] = a1[s]; }
  if (!diag) {
    const us8* sb = (const us8*)(pl + (size_t)(C * 64 + r) * 256 + R * 64 + c0);
    us8 b0 = sb[0], b1 = sb[1];
    #pragma unroll
    for (int s = 0; s < 8; ++s) { tb[r][c0 + s] = b0[s]; tb[r][c0 + 8 + s] = b1[s]; }
  }
  __syncthreads();
  us8 o0, o1;
  #pragma unroll
  for (int s = 0; s < 8; ++s) { o0[s] = ta[c0 + s][r]; o1[s] = ta[c0 + 8 + s][r]; }
  us8* da = (us8*)(pl + (size_t)(C * 64 + r) * 256 + R * 64 + c0);
  da[0] = o0; da[1] = o1;
  if (!diag) {
    us8 p0, p1;
    #pragma unroll
    for (int s = 0; s < 8; ++s) { p0[s] = tb[c0 + s][r]; p1[s] = tb[c0 + 8 + s][r]; }
    us8* db = (us8*)(pl + (size_t)(R * 64 + r) * 256 + C * 64 + c0);
    db[0] = p0; db[1] = p1;
  }
}

// ---------- row softmax over 256 fp32 -> bf16 P; one wave per row ----------
__global__ void softmax_kernel(const float* __restrict__ S, u16* __restrict__ P) {
  int row = blockIdx.x * 4 + (threadIdx.x >> 6);
  int lane = threadIdx.x & 63;
  f32x4 v = ((const f32x4*)(S + (size_t)row * 256))[lane];
  float mx = fmaxf(fmaxf(v[0], v[1]), fmaxf(v[2], v[3]));
  #pragma unroll
  for (int o = 32; o > 0; o >>= 1) mx = fmaxf(mx, __shfl_xor(mx, o));
  float e0 = __expf(v[0] - mx), e1 = __expf(v[1] - mx);
  float e2 = __expf(v[2] - mx), e3 = __expf(v[3] - mx);
  float sum = e0 + e1 + e2 + e3;
  #pragma unroll
  for (int o = 32; o > 0; o >>= 1) sum += __shfl_xor(sum, o);
  float inv = 1.0f / sum;
  ushort4 p;
  p.x = f2bf(e0 * inv); p.y = f2bf(e1 * inv); p.z = f2bf(e2 * inv); p.w = f2bf(e3 * inv);
  ((ushort4*)(P + (size_t)row * 256))[lane] = p;
}

extern "C" void kernel_launch(void* const* d_in, const int* in_sizes, int n_in,
                              void* d_out, int out_size, void* d_ws, size_t ws_size,
                              hipStream_t stream) {
  const float* x  = (const float*)d_in[0];   // [16384, 2048]
  const float* wq = (const float*)d_in[1];   // [6144, 2048]
  const float* wp = (const float*)d_in[2];   // [2048, 2048]
  const float* bp = (const float*)d_in[3];   // [2048]
  float* out = (float*)d_out;
  char* ws = (char*)d_ws;

  const size_t SZ_H   = (size_t)512 * 256 * 256 * 2;   // 64 MiB per-head tensor
  const size_t SZ_S   = (size_t)128 * 256 * 256 * 4;   // 32 MiB group S
  const size_t SZ_P   = (size_t)128 * 256 * 256 * 2;   // 16 MiB group P
  const size_t SZ_AT  = (size_t)16384 * 2048 * 2;      // 64 MiB attn bf16
  const size_t SZ_WP  = (size_t)2048 * 2048 * 2;       //  8 MiB wp bf16
  const size_t SZ_X   = (size_t)16384 * 2048 * 2;      // 64 MiB x hi or lo
  const size_t SZ_W   = (size_t)6144 * 2048 * 2;       // 24 MiB wq hi or lo
  const size_t NEED_MIN  = 5 * SZ_H + SZ_S + SZ_P + SZ_AT + SZ_WP;       // 440 MiB
  const size_t NEED_FAST = NEED_MIN + 2 * SZ_X + 2 * SZ_W;               // 616 MiB

  if (ws_size < NEED_MIN) {   // diagnostic: absmax ~= ws_size in MiB
    beacon_kernel<<<2048, 256, 0, stream>>>(out, (float)(ws_size >> 20), 16384 * 2048);
    return;
  }
  const bool fast = (ws_size >= NEED_FAST);

  u16* q_hi = (u16*)(ws);
  u16* q_lo = (u16*)(ws + SZ_H);
  u16* k_hi = (u16*)(ws + 2 * SZ_H);
  u16* k_lo = (u16*)(ws + 3 * SZ_H);
  u16* vbuf = (u16*)(ws + 4 * SZ_H);
  float* S  = (float*)(ws + 5 * SZ_H);
  u16* Pm   = (u16*)(ws + 5 * SZ_H + SZ_S);
  u16* attn = (u16*)(ws + 5 * SZ_H + SZ_S + SZ_P);
  u16* wpb  = (u16*)(ws + 5 * SZ_H + SZ_S + SZ_P + SZ_AT);
  u16* x_hi = (u16*)(ws + NEED_MIN);
  u16* x_lo = (u16*)(ws + NEED_MIN + SZ_X);
  u16* w_hi = (u16*)(ws + NEED_MIN + 2 * SZ_X);
  u16* w_lo = (u16*)(ws + NEED_MIN + 2 * SZ_X + SZ_W);

  split_kernel<<<2048, 256, 0, stream>>>(wp, wpb, nullptr, 2048 * 2048 / 4);

  // G1: qkv = x @ w_qkv.T  (split bf16, 3-term compensated)
  if (fast) {
    split_kernel<<<8192, 256, 0, stream>>>(x,  x_hi, x_lo, 16384 * 2048 / 4);
    split_kernel<<<4096, 256, 0, stream>>>(wq, w_hi, w_lo, 6144 * 2048 / 4);
    gemm_nt<0><<<dim3(128, 48, 1), 256, 0, stream>>>(
        x_hi, x_lo, w_hi, w_lo, nullptr, nullptr,
        q_hi, q_lo, k_hi, k_lo, vbuf, nullptr, nullptr, nullptr, nullptr,
        2048, 2048, 64, 0);
  } else {
    gemm_nt<4><<<dim3(128, 48, 1), 256, 0, stream>>>(
        nullptr, nullptr, nullptr, nullptr, x, wq,
        q_hi, q_lo, k_hi, k_lo, vbuf, nullptr, nullptr, nullptr, nullptr,
        2048, 2048, 64, 0);
  }

  // T: in-place per-head transpose of k (hi,lo) and v
  transpose_inplace<<<dim3(10, 512, 3), 256, 0, stream>>>(k_hi, k_lo, vbuf);

  // Attention in 4 groups of 128 planes (S, P reused per group; stream-ordered)
  for (int g = 0; g < 4; ++g) {
    int pb = g * 128;
    // G2: S^T[z][i][j] = sum_t kT[i,t] * q[j,t]  (split)
    gemm_nt<1><<<dim3(2, 2, 128), 256, 0, stream>>>(
        k_hi, k_lo, q_hi, q_lo, nullptr, nullptr,
        nullptr, nullptr, nullptr, nullptr, nullptr, S, nullptr, nullptr, nullptr,
        256, 256, 8, pb);
    softmax_kernel<<<8192, 256, 0, stream>>>(S, Pm);
    // G3: attn[(b*256+i)][(h*256+d)] = sum_j P[i,j] * vT[d,j]
    gemm_nt<2><<<dim3(2, 2, 128), 256, 0, stream>>>(
        Pm, nullptr, vbuf, nullptr, nullptr, nullptr,
        nullptr, nullptr, nullptr, nullptr, nullptr, nullptr, attn, nullptr, nullptr,
        256, 256, 8, pb);
  }

  // G4: out = attn @ w_proj.T + b_proj
  gemm_nt<3><<<dim3(128, 16, 1), 256, 0, stream>>>(
      attn, nullptr, wpb, nullptr, nullptr, nullptr,
      nullptr, nullptr, nullptr, nullptr, nullptr, nullptr, nullptr, out, bp,
      2048, 2048, 64, 0);
}

// Round 4
// 1546.518 us; speedup vs baseline: 1.3558x; 1.3558x over previous
//
#include <hip/hip_runtime.h>
#include <hip/hip_bf16.h>

typedef unsigned short u16;
typedef __attribute__((ext_vector_type(4))) float f32x4;
typedef __attribute__((ext_vector_type(8))) short short8;
typedef __attribute__((ext_vector_type(8))) u16 us8;

// Geometry (fixed): B=64, N=256, DIM=2048, H=8, D=256; M=B*N=16384; qkvN=6144
// Per-head planes: [512][256][256]

__device__ __forceinline__ u16 f2bf(float f) {
  union { float f; unsigned u; } v; v.f = f;
  unsigned r = v.u + 0x7fffu + ((v.u >> 16) & 1u);   // RNE, finite inputs
  return (u16)(r >> 16);
}
__device__ __forceinline__ float bf2f(u16 h) {
  union { unsigned u; float f; } v; v.u = ((unsigned)h) << 16; return v.f;
}

__global__ void beacon_kernel(float* __restrict__ out, float val, int n) {
  int stride = gridDim.x * blockDim.x;
  for (int i = blockIdx.x * blockDim.x + threadIdx.x; i < n; i += stride)
    out[i] = val;
}

__global__ void split_kernel(const float* __restrict__ in, u16* __restrict__ hi,
                             u16* __restrict__ lo, int n4) {
  int stride = gridDim.x * blockDim.x;
  for (int i = blockIdx.x * blockDim.x + threadIdx.x; i < n4; i += stride) {
    f32x4 v = ((const f32x4*)in)[i];
    ushort4 h;
    h.x = f2bf(v[0]); h.y = f2bf(v[1]); h.z = f2bf(v[2]); h.w = f2bf(v[3]);
    ((ushort4*)hi)[i] = h;
    if (lo) {
      ushort4 l;
      l.x = f2bf(v[0] - bf2f(h.x)); l.y = f2bf(v[1] - bf2f(h.y));
      l.z = f2bf(v[2] - bf2f(h.z)); l.w = f2bf(v[3] - bf2f(h.w));
      ((ushort4*)lo)[i] = l;
    }
  }
}

// ============ plain bf16 NT GEMM, m97 structure (HW-validated round 2) ============
// C[M,N] = sum over K of A[M,K]*B[N,K]^T, BK=32, 128x128 tile, 4 waves.
// K is a concatenation of up to 3 segments selected by (ks >> segShift);
// within-segment k0 = (ks & mask)*32.  Segments implement split-bf16
// compensation as plain GEMM over concatenated K.
// EPI 0: qkv->q,k scatter (hi+lo residual); EPI 1: qkv->v plane;
// EPI 2: logits -> fp32 S (z-batched);     EPI 3: PV -> bf16 attn;
// EPI 4: proj -> fp32 out + bias.
template<int EPI>
__global__ __launch_bounds__(256)
void gemm_nt(const u16* __restrict__ A0, const u16* __restrict__ A1, const u16* __restrict__ A2,
             const u16* __restrict__ B0, const u16* __restrict__ B1, const u16* __restrict__ B2,
             u16* __restrict__ qh, u16* __restrict__ ql,
             u16* __restrict__ kh, u16* __restrict__ kl,
             u16* __restrict__ vv,
             float* __restrict__ sout, u16* __restrict__ aout,
             float* __restrict__ fout, const float* __restrict__ bias,
             int ldA, int ldB, int ksteps, int segShift, int plane_base) {
  __shared__ __align__(16) u16 lds[8192];   // 2 slots x [128][32] bf16
  u16* sA = lds;
  u16* sB = lds + 4096;

  const int tid = threadIdx.x;
  const int wave = tid >> 6, lane = tid & 63;
  const int wr = wave >> 1, wc = wave & 1;
  const int l15 = lane & 15, l16 = lane >> 4;

  size_t zoffA = 0, zoffB = 0;
  if constexpr (EPI == 2) {
    size_t gz = (size_t)(plane_base + blockIdx.z) * 65536;
    zoffA = gz; zoffB = gz;
  }
  if constexpr (EPI == 3) {
    zoffA = (size_t)blockIdx.z * 65536;                 // P: group-local plane
    zoffB = (size_t)(plane_base + blockIdx.z) * 65536;  // vT: global plane
  }
  const u16* As[3] = {A0 + zoffA, A1 + zoffA, A2 + zoffA};
  const u16* Bs[3] = {B0 + zoffB, B1 + zoffB, B2 + zoffB};

  const int m0 = blockIdx.x * 128;
  const int n0 = blockIdx.y * 128;
  const int kmask = (1 << segShift) - 1;

  f32x4 acc[4][4] = {};

  auto stage = [&](const u16* gp, int ld, u16* slot, int row0, int k0) {
    #pragma unroll
    for (int c = 0; c < 2; ++c) {
      int chunk = wave + c * 4;
      int r = chunk * 16 + (lane >> 2);
      int col = (lane & 3) * 8;
      const u16* src = gp + (size_t)(row0 + r) * ld + (k0 + col);
      __builtin_amdgcn_global_load_lds(
          (const __attribute__((address_space(1))) unsigned*)src,
          (__attribute__((address_space(3))) unsigned*)(slot + chunk * 512), 16, 0, 0);
    }
  };

  for (int ks = 0; ks < ksteps; ++ks) {
    int seg = ks >> segShift;
    int k0 = (ks & kmask) * 32;
    stage(As[seg], ldA, sA, m0, k0);
    stage(Bs[seg], ldB, sB, n0, k0);
    __syncthreads();

    short8 a[4], b[4];
    #pragma unroll
    for (int i = 0; i < 4; ++i) {
      int ra = (wr * 64 + i * 16 + l15) * 4 + l16;   // short8 idx in [128][32]
      int rb = (wc * 64 + i * 16 + l15) * 4 + l16;
      a[i] = ((const short8*)sA)[ra];
      b[i] = ((const short8*)sB)[rb];
    }
    #pragma unroll
    for (int i = 0; i < 4; ++i)
      #pragma unroll
      for (int j = 0; j < 4; ++j)
        acc[i][j] = __builtin_amdgcn_mfma_f32_16x16x32_bf16(a[i], b[j], acc[i][j], 0, 0, 0);
    __syncthreads();
  }

  // epilogue: C/D layout (m89/m91): col = lane&15, row = (lane>>4)*4 + reg
  #pragma unroll
  for (int i = 0; i < 4; ++i)
    #pragma unroll
    for (int j = 0; j < 4; ++j)
      #pragma unroll
      for (int r = 0; r < 4; ++r) {
        int gm = m0 + wr * 64 + i * 16 + l16 * 4 + r;
        int gn = n0 + wc * 64 + j * 16 + l15;
        float val = acc[i][j][r];
        if constexpr (EPI == 0) {
          int b = gm >> 8, tok = gm & 255;
          int sel = gn >> 11, head = (gn >> 8) & 7, col = gn & 255;
          size_t addr = (((size_t)b * 8 + head) * 256 + tok) * 256 + col;
          u16 h = f2bf(val), lo = f2bf(val - bf2f(h));
          if (sel == 0) { qh[addr] = h; ql[addr] = lo; }
          else          { kh[addr] = h; kl[addr] = lo; }
        } else if constexpr (EPI == 1) {
          int b = gm >> 8, tok = gm & 255;
          int head = (gn >> 8) & 7, col = gn & 255;
          size_t addr = (((size_t)b * 8 + head) * 256 + tok) * 256 + col;
          vv[addr] = f2bf(val);
        } else if constexpr (EPI == 2) {
          sout[(size_t)blockIdx.z * 65536 + (size_t)gm * 256 + gn] = val;
        } else if constexpr (EPI == 3) {
          int gp = plane_base + blockIdx.z;
          size_t row = (size_t)(gp >> 3) * 256 + gm;
          size_t col = (size_t)(gp & 7) * 256 + gn;
          aout[row * 2048 + col] = f2bf(val);
        } else {
          fout[(size_t)gm * 2048 + gn] = val + bias[gn];
        }
      }
}

// ---------- per-head 256x256 in-place transpose (k_hi, k_lo, v) ----------
__global__ void transpose_inplace(u16* __restrict__ kh, u16* __restrict__ kl,
                                  u16* __restrict__ v) {
  __shared__ u16 ta[64][66], tb[64][66];
  u16* base = (blockIdx.z == 0) ? kh : (blockIdx.z == 1) ? kl : v;
  u16* pl = base + (size_t)blockIdx.y * 65536;
  const int RA[10] = {0,1,2,3, 0,0,0,1,1,2};
  const int CA[10] = {0,1,2,3, 1,2,3,2,3,3};
  int p = blockIdx.x;
  int R = RA[p], C = CA[p];
  bool diag = (R == C);
  int tid = threadIdx.x;
  int r = tid >> 2, c0 = (tid & 3) * 16;

  const us8* sa = (const us8*)(pl + (size_t)(R * 64 + r) * 256 + C * 64 + c0);
  us8 a0 = sa[0], a1 = sa[1];
  #pragma unroll
  for (int s = 0; s < 8; ++s) { ta[r][c0 + s] = a0[s]; ta[r][c0 + 8 + s] = a1[s]; }
  if (!diag) {
    const us8* sb = (const us8*)(pl + (size_t)(C * 64 + r) * 256 + R * 64 + c0);
    us8 b0 = sb[0], b1 = sb[1];
    #pragma unroll
    for (int s = 0; s < 8; ++s) { tb[r][c0 + s] = b0[s]; tb[r][c0 + 8 + s] = b1[s]; }
  }
  __syncthreads();
  us8 o0, o1;
  #pragma unroll
  for (int s = 0; s < 8; ++s) { o0[s] = ta[c0 + s][r]; o1[s] = ta[c0 + 8 + s][r]; }
  us8* da = (us8*)(pl + (size_t)(C * 64 + r) * 256 + R * 64 + c0);
  da[0] = o0; da[1] = o1;
  if (!diag) {
    us8 p0, p1;
    #pragma unroll
    for (int s = 0; s < 8; ++s) { p0[s] = tb[c0 + s][r]; p1[s] = tb[c0 + 8 + s][r]; }
    us8* db = (us8*)(pl + (size_t)(R * 64 + r) * 256 + C * 64 + c0);
    db[0] = p0; db[1] = p1;
  }
}

// ---------- row softmax over 256 fp32 -> bf16 P; one wave per row ----------
__global__ void softmax_kernel(const float* __restrict__ S, u16* __restrict__ P) {
  int row = blockIdx.x * 4 + (threadIdx.x >> 6);
  int lane = threadIdx.x & 63;
  f32x4 v = ((const f32x4*)(S + (size_t)row * 256))[lane];
  float mx = fmaxf(fmaxf(v[0], v[1]), fmaxf(v[2], v[3]));
  #pragma unroll
  for (int o = 32; o > 0; o >>= 1) mx = fmaxf(mx, __shfl_xor(mx, o));
  float e0 = __expf(v[0] - mx), e1 = __expf(v[1] - mx);
  float e2 = __expf(v[2] - mx), e3 = __expf(v[3] - mx);
  float sum = e0 + e1 + e2 + e3;
  #pragma unroll
  for (int o = 32; o > 0; o >>= 1) sum += __shfl_xor(sum, o);
  float inv = 1.0f / sum;
  ushort4 p;
  p.x = f2bf(e0 * inv); p.y = f2bf(e1 * inv); p.z = f2bf(e2 * inv); p.w = f2bf(e3 * inv);
  ((ushort4*)(P + (size_t)row * 256))[lane] = p;
}

extern "C" void kernel_launch(void* const* d_in, const int* in_sizes, int n_in,
                              void* d_out, int out_size, void* d_ws, size_t ws_size,
                              hipStream_t stream) {
  const float* x  = (const float*)d_in[0];   // [16384, 2048]
  const float* wq = (const float*)d_in[1];   // [6144, 2048]
  const float* wp = (const float*)d_in[2];   // [2048, 2048]
  const float* bp = (const float*)d_in[3];   // [2048]
  float* out = (float*)d_out;
  char* ws = (char*)d_ws;

  const size_t MB = 1ull << 20;
  const size_t NEED = 432 * MB;
  if (ws_size < NEED) {
    beacon_kernel<<<2048, 256, 0, stream>>>(out, (float)(ws_size >> 20), 16384 * 2048);
    return;
  }

  // persistent per-head tensors [0, 320 MiB)
  u16* q_hi = (u16*)(ws);
  u16* q_lo = (u16*)(ws + 64 * MB);
  u16* k_hi = (u16*)(ws + 128 * MB);
  u16* k_lo = (u16*)(ws + 192 * MB);
  u16* vbuf = (u16*)(ws + 256 * MB);
  // G1 phase window [320, 432 MiB)
  u16* x_hi = (u16*)(ws + 320 * MB);   // 64 MiB (no x_lo needed)
  u16* w_hi = (u16*)(ws + 384 * MB);   // 24 MiB
  u16* w_lo = (u16*)(ws + 408 * MB);   // 24 MiB
  // attention phase window (x, w dead)
  float* S  = (float*)(ws + 320 * MB); // 32 MiB
  u16* Pm   = (u16*)(ws + 352 * MB);   // 16 MiB
  u16* attn = (u16*)(ws + 368 * MB);   // 64 MiB (lives into proj)
  u16* wpb  = (u16*)(ws + 320 * MB);   //  8 MiB (over dead S)

  // prep: x -> hi only; w_qkv -> hi+lo
  split_kernel<<<8192, 256, 0, stream>>>(x,  x_hi, nullptr, 16384 * 2048 / 4);
  split_kernel<<<4096, 256, 0, stream>>>(wq, w_hi, w_lo, 6144 * 2048 / 4);

  // G1 qk: q,k = x_hi @ (w_hi + w_lo)^T  (2 K-segments of 2048)
  gemm_nt<0><<<dim3(128, 32, 1), 256, 0, stream>>>(
      x_hi, x_hi, x_hi, w_hi, w_lo, w_hi,
      q_hi, q_lo, k_hi, k_lo, nullptr, nullptr, nullptr, nullptr, nullptr,
      2048, 2048, 128, 6, 0);
  // G1 v: v = x_hi @ wv_hi^T  (1 segment)
  const u16* wv = w_hi + (size_t)4096 * 2048;
  gemm_nt<1><<<dim3(128, 16, 1), 256, 0, stream>>>(
      x_hi, x_hi, x_hi, wv, wv, wv,
      nullptr, nullptr, nullptr, nullptr, vbuf, nullptr, nullptr, nullptr, nullptr,
      2048, 2048, 64, 6, 0);

  // in-place per-head transpose of k (hi,lo) and v
  transpose_inplace<<<dim3(10, 512, 3), 256, 0, stream>>>(k_hi, k_lo, vbuf);

  // attention in 4 groups of 128 planes
  for (int gp = 0; gp < 4; ++gp) {
    int pb = gp * 128;
    // S^T = kT*q^T, 3-term compensation as 3 K-segments of 256
    gemm_nt<2><<<dim3(2, 2, 128), 256, 0, stream>>>(
        k_hi, k_hi, k_lo, q_hi, q_lo, q_hi,
        nullptr, nullptr, nullptr, nullptr, nullptr, S, nullptr, nullptr, nullptr,
        256, 256, 24, 3, pb);
    softmax_kernel<<<8192, 256, 0, stream>>>(S, Pm);
    // PV: attn = P @ vT^T
    gemm_nt<3><<<dim3(2, 2, 128), 256, 0, stream>>>(
        Pm, Pm, Pm, vbuf, vbuf, vbuf,
        nullptr, nullptr, nullptr, nullptr, nullptr, nullptr, attn, nullptr, nullptr,
        256, 256, 8, 3, pb);
  }

  // proj: out = attn @ wp^T + bias
  split_kernel<<<2048, 256, 0, stream>>>(wp, wpb, nullptr, 2048 * 2048 / 4);
  gemm_nt<4><<<dim3(128, 16, 1), 256, 0, stream>>>(
      attn, attn, attn, wpb, wpb, wpb,
      nullptr, nullptr, nullptr, nullptr, nullptr, nullptr, nullptr, out, bp,
      2048, 2048, 64, 6, 0);
}